// Round 1
// baseline (3083.360 us; speedup 1.0000x reference)
//
#include <hip/hip_runtime.h>
#include <hip/hip_bf16.h>

#define TC_C   256
#define TC_HD  256
#define TC_D   64

// workspace layout (floats)
#define WS_SSQ_Q 0
#define WS_SSQ_K 1
#define WS_KSUM  64                    // 256 floats
#define WS_KV    1024                  // 16384 floats (kv[h][m][d])
#define WS_FLOATS (1024 + TC_HD * TC_D)

// ---------------- kernel 1a: ssq over q = query @ Wq^T + bq ----------------
__global__ __launch_bounds__(256)
void k_ssq_q(const float* __restrict__ x, const float* __restrict__ W,
             const float* __restrict__ b, float* __restrict__ ws, int N)
{
    constexpr int CH = 16;
    __shared__ float xs[CH][TC_C];
    __shared__ float red[256];
    const int t = threadIdx.x;
    const float bv = b[t];
    float ssq = 0.f;
    const float4* w4 = (const float4*)&W[t * TC_C];
    const int nch = (N + CH - 1) / CH;
    for (int ch = blockIdx.x; ch < nch; ch += gridDim.x) {
        const int row0 = ch * CH;
        const int nr = min(CH, N - row0);
        __syncthreads();
        for (int i = t; i < nr * (TC_C / 4); i += 256) {
            const int r = i >> 6, cc = (i & 63) << 2;
            *(float4*)&xs[r][cc] = *(const float4*)&x[(size_t)(row0 + r) * TC_C + cc];
        }
        __syncthreads();
        float acc[CH];
#pragma unroll
        for (int r = 0; r < CH; ++r) acc[r] = bv;
#pragma unroll 4
        for (int c4 = 0; c4 < TC_C / 4; ++c4) {
            const float4 w = w4[c4];
#pragma unroll
            for (int r = 0; r < CH; ++r) {
                const float4 xv = *(const float4*)&xs[r][c4 * 4];
                acc[r] = fmaf(xv.x, w.x, fmaf(xv.y, w.y, fmaf(xv.z, w.z, fmaf(xv.w, w.w, acc[r]))));
            }
        }
#pragma unroll
        for (int r = 0; r < CH; ++r)
            if (r < nr) ssq = fmaf(acc[r], acc[r], ssq);
    }
    red[t] = ssq;
    __syncthreads();
    if (t < 128) red[t] += red[t + 128];
    __syncthreads();
    if (t < 64) red[t] += red[t + 64];
    __syncthreads();
    if (t == 0) {
        float s = 0.f;
        for (int i = 0; i < 64; ++i) s += red[i];
        atomicAdd(&ws[WS_SSQ_Q], s);
    }
}

// -------- kernel 1b: k,v = source proj; reduce ssq_k, ksum, kv = k^T v --------
__global__ __launch_bounds__(256)
void k_reduce_src(const float* __restrict__ x,
                  const float* __restrict__ Wk, const float* __restrict__ bk,
                  const float* __restrict__ Wv, const float* __restrict__ bv,
                  float* __restrict__ ws, int N)
{
    constexpr int CH = 16;
    __shared__ float xs[CH][TC_C];
    __shared__ float vs[CH][TC_HD];
    __shared__ float red[256];
    const int t = threadIdx.x;
    const int h = t >> 6;               // thread t owns k-column t = h*64+m
    const float bkv = bk[t], bvv = bv[t];
    float kvacc[TC_D];
#pragma unroll
    for (int d = 0; d < TC_D; ++d) kvacc[d] = 0.f;
    float ksum_acc = 0.f, ssq_acc = 0.f;
    const float4* wk4 = (const float4*)&Wk[t * TC_C];
    const float4* wv4 = (const float4*)&Wv[t * TC_C];
    const int nch = (N + CH - 1) / CH;
    for (int ch = blockIdx.x; ch < nch; ch += gridDim.x) {
        const int row0 = ch * CH;
        const int nr = min(CH, N - row0);
        __syncthreads();
        for (int i = t; i < nr * (TC_C / 4); i += 256) {
            const int r = i >> 6, cc = (i & 63) << 2;
            *(float4*)&xs[r][cc] = *(const float4*)&x[(size_t)(row0 + r) * TC_C + cc];
        }
        __syncthreads();
        float ak[CH], av[CH];
#pragma unroll
        for (int r = 0; r < CH; ++r) { ak[r] = bkv; av[r] = bvv; }
#pragma unroll 4
        for (int c4 = 0; c4 < TC_C / 4; ++c4) {
            const float4 wk = wk4[c4];
            const float4 wv = wv4[c4];
#pragma unroll
            for (int r = 0; r < CH; ++r) {
                const float4 xv = *(const float4*)&xs[r][c4 * 4];
                ak[r] = fmaf(xv.x, wk.x, fmaf(xv.y, wk.y, fmaf(xv.z, wk.z, fmaf(xv.w, wk.w, ak[r]))));
                av[r] = fmaf(xv.x, wv.x, fmaf(xv.y, wv.y, fmaf(xv.z, wv.z, fmaf(xv.w, wv.w, av[r]))));
            }
        }
#pragma unroll
        for (int r = 0; r < CH; ++r) vs[r][t] = av[r];
        __syncthreads();
#pragma unroll
        for (int r = 0; r < CH; ++r) {
            if (r < nr) {
                const float kk = ak[r];
                ksum_acc += kk;
                ssq_acc = fmaf(kk, kk, ssq_acc);
                const float4* vrow = (const float4*)&vs[r][h * TC_D];  // broadcast within wave
#pragma unroll
                for (int d4 = 0; d4 < TC_D / 4; ++d4) {
                    const float4 vv = vrow[d4];
                    kvacc[d4 * 4 + 0] = fmaf(kk, vv.x, kvacc[d4 * 4 + 0]);
                    kvacc[d4 * 4 + 1] = fmaf(kk, vv.y, kvacc[d4 * 4 + 1]);
                    kvacc[d4 * 4 + 2] = fmaf(kk, vv.z, kvacc[d4 * 4 + 2]);
                    kvacc[d4 * 4 + 3] = fmaf(kk, vv.w, kvacc[d4 * 4 + 3]);
                }
            }
        }
    }
    atomicAdd(&ws[WS_KSUM + t], ksum_acc);
#pragma unroll
    for (int d = 0; d < TC_D; ++d)
        atomicAdd(&ws[WS_KV + t * TC_D + d], kvacc[d]);
    red[t] = ssq_acc;
    __syncthreads();
    if (t < 128) red[t] += red[t + 128];
    __syncthreads();
    if (t < 64) red[t] += red[t + 64];
    __syncthreads();
    if (t == 0) {
        float s = 0.f;
        for (int i = 0; i < 64; ++i) s += red[i];
        atomicAdd(&ws[WS_SSQ_K], s);
    }
}

// -------- kernel 2: recompute q,v per row; combine with kv/ksum; write out --------
__global__ __launch_bounds__(256)
void k_finalize(const float* __restrict__ qx, const float* __restrict__ sx,
                const float* __restrict__ Wq, const float* __restrict__ bq,
                const float* __restrict__ Wv, const float* __restrict__ bv,
                const float* __restrict__ ws, float* __restrict__ out, int N)
{
    constexpr int CH = 16;
    __shared__ float kvn[TC_HD * TC_D];   // 64 KiB, scal-folded
    __shared__ float ksn[TC_HD];
    __shared__ float xs[CH][TC_C];
    __shared__ float qsl[CH][TC_HD];
    const int t = threadIdx.x;
    const int h = t >> 6;
    const float scal = rsqrtf(ws[WS_SSQ_Q]) * rsqrtf(ws[WS_SSQ_K]);
    for (int i = t; i < TC_HD * TC_D; i += 256)
        kvn[i] = ws[WS_KV + i] * scal;
    ksn[t] = ws[WS_KSUM + t] * scal;
    const float bqv = bq[t], bvv = bv[t];
    const float fN = (float)N;
    const float4* wq4 = (const float4*)&Wq[t * TC_C];
    const float4* wv4 = (const float4*)&Wv[t * TC_C];
    const int nch = (N + CH - 1) / CH;
    for (int ch = blockIdx.x; ch < nch; ch += gridDim.x) {
        const int row0 = ch * CH;
        const int nr = min(CH, N - row0);
        __syncthreads();   // guards xs reuse from prev iter; first iter: kvn/ksn visible
        for (int i = t; i < nr * (TC_C / 4); i += 256) {
            const int r = i >> 6, cc = (i & 63) << 2;
            *(float4*)&xs[r][cc] = *(const float4*)&qx[(size_t)(row0 + r) * TC_C + cc];
        }
        __syncthreads();
        float aq[CH];
#pragma unroll
        for (int r = 0; r < CH; ++r) aq[r] = bqv;
#pragma unroll 4
        for (int c4 = 0; c4 < TC_C / 4; ++c4) {
            const float4 w = wq4[c4];
#pragma unroll
            for (int r = 0; r < CH; ++r) {
                const float4 xv = *(const float4*)&xs[r][c4 * 4];
                aq[r] = fmaf(xv.x, w.x, fmaf(xv.y, w.y, fmaf(xv.z, w.z, fmaf(xv.w, w.w, aq[r]))));
            }
        }
#pragma unroll
        for (int r = 0; r < CH; ++r) qsl[r][t] = aq[r];
        __syncthreads();   // xs free for reuse, qsl visible
        for (int i = t; i < nr * (TC_C / 4); i += 256) {
            const int r = i >> 6, cc = (i & 63) << 2;
            *(float4*)&xs[r][cc] = *(const float4*)&sx[(size_t)(row0 + r) * TC_C + cc];
        }
        __syncthreads();
        float av[CH];
#pragma unroll
        for (int r = 0; r < CH; ++r) av[r] = bvv;
#pragma unroll 4
        for (int c4 = 0; c4 < TC_C / 4; ++c4) {
            const float4 w = wv4[c4];
#pragma unroll
            for (int r = 0; r < CH; ++r) {
                const float4 xv = *(const float4*)&xs[r][c4 * 4];
                av[r] = fmaf(xv.x, w.x, fmaf(xv.y, w.y, fmaf(xv.z, w.z, fmaf(xv.w, w.w, av[r]))));
            }
        }
        __syncthreads();   // done reading xs; reuse as contrib buffer
        float num[CH], den[CH];
#pragma unroll
        for (int r = 0; r < CH; ++r) { num[r] = fN * av[r]; den[r] = fN; }
        const float* kvh = &kvn[h * 64 * 64 + (t & 63)];
        const float* ksh = &ksn[h * 64];
#pragma unroll 4
        for (int m = 0; m < 64; ++m) {
            const float kvv = kvh[m * 64];
            const float ksv = ksh[m];
#pragma unroll
            for (int r = 0; r < CH; ++r) {
                const float qv = qsl[r][h * 64 + m];   // broadcast within wave
                num[r] = fmaf(qv, kvv, num[r]);
                den[r] = fmaf(qv, ksv, den[r]);
            }
        }
#pragma unroll
        for (int r = 0; r < CH; ++r)
            if (r < nr) xs[r][t] = 0.25f * num[r] / den[r];
        __syncthreads();
        for (int i = t; i < nr * TC_D; i += 256) {
            const int r = i >> 6, dd = i & 63;
            out[(size_t)(row0 + r) * TC_D + dd] =
                xs[r][dd] + xs[r][TC_D + dd] + xs[r][2 * TC_D + dd] + xs[r][3 * TC_D + dd];
        }
    }
}

extern "C" void kernel_launch(void* const* d_in, const int* in_sizes, int n_in,
                              void* d_out, int out_size, void* d_ws, size_t ws_size,
                              hipStream_t stream)
{
    const float* qx = (const float*)d_in[0];
    const float* sx = (const float*)d_in[1];
    const float* Wq = (const float*)d_in[2];
    const float* bq = (const float*)d_in[3];
    const float* Wk = (const float*)d_in[4];
    const float* bk = (const float*)d_in[5];
    const float* Wv = (const float*)d_in[6];
    const float* bv = (const float*)d_in[7];
    float* out = (float*)d_out;
    float* ws = (float*)d_ws;
    const int N = in_sizes[0] / TC_C;

    hipMemsetAsync(d_ws, 0, WS_FLOATS * sizeof(float), stream);
    k_ssq_q<<<512, 256, 0, stream>>>(qx, Wq, bq, ws, N);
    k_reduce_src<<<512, 256, 0, stream>>>(sx, Wk, bk, Wv, bv, ws, N);
    k_finalize<<<512, 256, 0, stream>>>(qx, sx, Wq, bq, Wv, bv, ws, out, N);
}

// Round 2
// 35.571 us; speedup vs baseline: 86.6807x; 86.6807x over previous
//
#include <hip/hip_runtime.h>
#include <hip/hip_bf16.h>

typedef short short8 __attribute__((ext_vector_type(8)));
typedef float f32x4 __attribute__((ext_vector_type(4)));

__device__ inline unsigned short f2bf(float f) {
    unsigned u = __builtin_bit_cast(unsigned, f);
    u += 0x7FFFu + ((u >> 16) & 1u);          // round-to-nearest-even
    return (unsigned short)(u >> 16);
}

// ---------------------------------------------------------------------------
// prep: Wm[d][c] = 0.25 * sum_h Wv[h*64+d][c], packed in MFMA B-fragment order:
//   Bf[((ct*8+kc)*64 + lane)*8 + j] = bf16(Wm[ct*16 + lane%16][kc*32 + (lane/16)*8 + j])
// bm[d] = 0.25 * sum_h bv[h*64+d]
// ---------------------------------------------------------------------------
__global__ __launch_bounds__(256)
void k_prep(const float* __restrict__ Wv, const float* __restrict__ bv,
            unsigned short* __restrict__ Bf, float* __restrict__ bm)
{
    const int t = blockIdx.x * 256 + threadIdx.x;   // 0..16383
    const int fi = t >> 9;                          // fragment index 0..31
    const int lane = (t >> 3) & 63;
    const int j = t & 7;
    const int ct = fi >> 3, kc = fi & 7;
    const int d = ct * 16 + (lane & 15);
    const int c = kc * 32 + (lane >> 4) * 8 + j;
    const float s = 0.25f * (Wv[(size_t)d * 256 + c] +
                             Wv[(size_t)(64 + d) * 256 + c] +
                             Wv[(size_t)(128 + d) * 256 + c] +
                             Wv[(size_t)(192 + d) * 256 + c]);
    Bf[t] = f2bf(s);
    if (t < 64)
        bm[t] = 0.25f * (bv[t] + bv[64 + t] + bv[128 + t] + bv[192 + t]);
}

// ---------------------------------------------------------------------------
// main: out[n][d] = sum_c source[n][c] * Wm[d][c] + bm[d]
// block = 256 threads = 4 waves; block owns 64 rows; wave w owns rows
// [blk*64 + w*16, +16); each wave computes all 64 output cols via 4 col-tiles.
// A (rows) read directly from global (16 dwordx4 in flight per lane),
// B staged once per block into LDS (linear layout -> conflict-free b128 reads).
// ---------------------------------------------------------------------------
__global__ __launch_bounds__(256)
void k_vmean(const float* __restrict__ X, const unsigned short* __restrict__ Bf,
             const float* __restrict__ bm, float* __restrict__ out, int N)
{
    __shared__ unsigned short Bs[16384];            // 32 KB

    const int t = threadIdx.x;
    // stage B fragments (coalesced 4 KB per iteration)
#pragma unroll
    for (int i = 0; i < 8; ++i)
        *(short8*)&Bs[(i * 256 + t) * 8] = *(const short8*)&Bf[(i * 256 + t) * 8];

    const int wave = t >> 6, lane = t & 63;
    const int arow = blockIdx.x * 64 + wave * 16 + (lane & 15);
    const int kgrp = lane >> 4;                     // 0..3
    const float* xrow = X + (size_t)(arow < N ? arow : N - 1) * 256 + kgrp * 8;

    // issue all 16 global loads (8 K-chunks x 32 B) up front
    float4 a0[8], a1[8];
#pragma unroll
    for (int kc = 0; kc < 8; ++kc) {
        a0[kc] = *(const float4*)(xrow + kc * 32);
        a1[kc] = *(const float4*)(xrow + kc * 32 + 4);
    }

    __syncthreads();                                // Bs ready

    f32x4 acc[4] = {};
#pragma unroll
    for (int kc = 0; kc < 8; ++kc) {
        short8 a;
        a[0] = (short)f2bf(a0[kc].x); a[1] = (short)f2bf(a0[kc].y);
        a[2] = (short)f2bf(a0[kc].z); a[3] = (short)f2bf(a0[kc].w);
        a[4] = (short)f2bf(a1[kc].x); a[5] = (short)f2bf(a1[kc].y);
        a[6] = (short)f2bf(a1[kc].z); a[7] = (short)f2bf(a1[kc].w);
#pragma unroll
        for (int ct = 0; ct < 4; ++ct) {
            const short8 b = *(const short8*)&Bs[((ct * 8 + kc) * 64 + lane) * 8];
            acc[ct] = __builtin_amdgcn_mfma_f32_16x16x32_bf16(a, b, acc[ct], 0, 0, 0);
        }
    }

    // epilogue: C/D layout col = lane&15, row = (lane>>4)*4 + reg  [m89-verified]
    const int orow0 = blockIdx.x * 64 + wave * 16 + (lane >> 4) * 4;
    const int col_lo = lane & 15;
#pragma unroll
    for (int ct = 0; ct < 4; ++ct) {
        const int col = ct * 16 + col_lo;
        const float bias = bm[col];
#pragma unroll
        for (int r = 0; r < 4; ++r) {
            const int row = orow0 + r;
            if (row < N)
                out[(size_t)row * 64 + col] = acc[ct][r] + bias;
        }
    }
}

extern "C" void kernel_launch(void* const* d_in, const int* in_sizes, int n_in,
                              void* d_out, int out_size, void* d_ws, size_t ws_size,
                              hipStream_t stream)
{
    const float* sx = (const float*)d_in[1];        // source_input
    const float* Wv = (const float*)d_in[6];
    const float* bv = (const float*)d_in[7];
    float* out = (float*)d_out;

    unsigned short* Bf = (unsigned short*)d_ws;                 // 32 KB
    float* bm = (float*)((char*)d_ws + 16384 * sizeof(unsigned short));

    const int N = in_sizes[0] / 256;
    const int nblk = (N + 63) / 64;

    k_prep<<<64, 256, 0, stream>>>(Wv, bv, Bf, bm);
    k_vmean<<<nblk, 256, 0, stream>>>(sx, Bf, bm, out, N);
}

// Round 3
// 34.282 us; speedup vs baseline: 89.9418x; 1.0376x over previous
//
#include <hip/hip_runtime.h>
#include <hip/hip_bf16.h>

typedef short short8 __attribute__((ext_vector_type(8)));
typedef float f32x4 __attribute__((ext_vector_type(4)));

__device__ inline unsigned short f2bf(float f) {
    unsigned u = __builtin_bit_cast(unsigned, f);
    u += 0x7FFFu + ((u >> 16) & 1u);          // round-to-nearest-even
    return (unsigned short)(u >> 16);
}

// ---------------------------------------------------------------------------
// prep: Wm[d][c] = 0.25 * sum_h Wv[h*64+d][c], packed in MFMA B-fragment order:
//   Bf[((ct*8+kc)*64 + lane)*8 + j] = bf16(Wm[ct*16 + lane%16][kc*32 + (lane/16)*8 + j])
// bm[d] = 0.25 * sum_h bv[h*64+d]
// ---------------------------------------------------------------------------
__global__ __launch_bounds__(256)
void k_prep(const float* __restrict__ Wv, const float* __restrict__ bv,
            unsigned short* __restrict__ Bf, float* __restrict__ bm)
{
    const int t = blockIdx.x * 256 + threadIdx.x;   // 0..16383
    const int fi = t >> 9;                          // fragment index 0..31
    const int lane = (t >> 3) & 63;
    const int j = t & 7;
    const int ct = fi >> 3, kc = fi & 7;
    const int d = ct * 16 + (lane & 15);
    const int c = kc * 32 + (lane >> 4) * 8 + j;
    const float s = 0.25f * (Wv[(size_t)d * 256 + c] +
                             Wv[(size_t)(64 + d) * 256 + c] +
                             Wv[(size_t)(128 + d) * 256 + c] +
                             Wv[(size_t)(192 + d) * 256 + c]);
    Bf[t] = f2bf(s);
    if (t < 64)
        bm[t] = 0.25f * (bv[t] + bv[64 + t] + bv[128 + t] + bv[192 + t]);
}

// ---------------------------------------------------------------------------
// main: out[n][d] = sum_c source[n][c] * Wm[d][c] + bm[d]
// 256 threads = 4 waves; block owns 64 rows; wave w owns rows
// [blk*64 + w*16, +16). No LDS, no barriers: B fragments (32 KB total,
// shared by all blocks) are read from global and served by each XCD's L2;
// X rows stream from HBM with all 16 loads/lane in flight.
// ---------------------------------------------------------------------------
__global__ __launch_bounds__(256)
void k_vmean(const float* __restrict__ X, const unsigned short* __restrict__ Bf,
             const float* __restrict__ bm, float* __restrict__ out, int N)
{
    const int t = threadIdx.x;
    const int wave = t >> 6, lane = t & 63;
    const int arow = blockIdx.x * 64 + wave * 16 + (lane & 15);
    const int kgrp = lane >> 4;                     // 0..3
    const float* xrow = X + (size_t)(arow < N ? arow : N - 1) * 256 + kgrp * 8;

    // issue all 16 X loads (8 K-chunks x 32 B per lane) up front
    float4 a0[8], a1[8];
#pragma unroll
    for (int kc = 0; kc < 8; ++kc) {
        a0[kc] = *(const float4*)(xrow + kc * 32);
        a1[kc] = *(const float4*)(xrow + kc * 32 + 4);
    }

    // bias regs (L2-hot, tiny)
    const int col_lo = lane & 15;
    float bias[4];
#pragma unroll
    for (int ct = 0; ct < 4; ++ct) bias[ct] = bm[ct * 16 + col_lo];

    f32x4 acc[4] = {};
#pragma unroll
    for (int kc = 0; kc < 8; ++kc) {
        short8 a;
        a[0] = (short)f2bf(a0[kc].x); a[1] = (short)f2bf(a0[kc].y);
        a[2] = (short)f2bf(a0[kc].z); a[3] = (short)f2bf(a0[kc].w);
        a[4] = (short)f2bf(a1[kc].x); a[5] = (short)f2bf(a1[kc].y);
        a[6] = (short)f2bf(a1[kc].z); a[7] = (short)f2bf(a1[kc].w);
#pragma unroll
        for (int ct = 0; ct < 4; ++ct) {
            const short8 b = *(const short8*)&Bf[((ct * 8 + kc) * 64 + lane) * 8];
            acc[ct] = __builtin_amdgcn_mfma_f32_16x16x32_bf16(a, b, acc[ct], 0, 0, 0);
        }
    }

    // epilogue: C/D layout col = lane&15, row = (lane>>4)*4 + reg  [m89-verified]
    const int orow0 = blockIdx.x * 64 + wave * 16 + (lane >> 4) * 4;
#pragma unroll
    for (int ct = 0; ct < 4; ++ct) {
        const int col = ct * 16 + col_lo;
#pragma unroll
        for (int r = 0; r < 4; ++r) {
            const int row = orow0 + r;
            if (row < N)
                out[(size_t)row * 64 + col] = acc[ct][r] + bias[ct];
        }
    }
}

extern "C" void kernel_launch(void* const* d_in, const int* in_sizes, int n_in,
                              void* d_out, int out_size, void* d_ws, size_t ws_size,
                              hipStream_t stream)
{
    const float* sx = (const float*)d_in[1];        // source_input
    const float* Wv = (const float*)d_in[6];
    const float* bv = (const float*)d_in[7];
    float* out = (float*)d_out;

    unsigned short* Bf = (unsigned short*)d_ws;                 // 32 KB
    float* bm = (float*)((char*)d_ws + 16384 * sizeof(unsigned short));

    const int N = in_sizes[0] / 256;
    const int nblk = (N + 63) / 64;

    k_prep<<<64, 256, 0, stream>>>(Wv, bv, Bf, bm);
    k_vmean<<<nblk, 256, 0, stream>>>(sx, Bf, bm, out, N);
}